// Round 1
// baseline (252.200 us; speedup 1.0000x reference)
//
#include <hip/hip_runtime.h>
#include <math.h>

#define BATCH 64
#define HH 512
#define WW 512
#define TH 32          // output rows per block strip
#define KS 11
#define PADK 5
#define NPIX (64.0 * 512.0 * 512.0)

// One block: 512 threads = one full image row width; strip of TH output rows.
// Separable 11x11 Gaussian conv of {a, b, a^2, b^2, ab} via:
//   per-row horizontal 11-tap conv (LDS row buffer, zero-padded),
//   vertical 11-tap conv via register shift-ring,
// then pointwise SSIM and block reduction -> atomicAdd(double).
__global__ void __launch_bounds__(WW) ssim_main_kernel(
    const float* __restrict__ img1, const float* __restrict__ img2,
    double* __restrict__ accum) {
  const int c  = threadIdx.x;            // column 0..511
  const int r0 = blockIdx.x * TH;        // first output row of this strip
  const int b  = blockIdx.y;             // batch index

  // Gaussian window (sigma = 1.5), normalized. ~1e-7 rel error vs numpy fp64.
  float g[KS];
  {
    float s = 0.f;
#pragma unroll
    for (int i = 0; i < KS; ++i) {
      float d = (float)(i - PADK);
      g[i] = __expf(-(d * d) * (1.0f / 4.5f));
      s += g[i];
    }
    float inv = 1.0f / s;
#pragma unroll
    for (int i = 0; i < KS; ++i) g[i] *= inv;
  }

  const float* p1 = img1 + (size_t)b * (HH * WW);
  const float* p2 = img2 + (size_t)b * (HH * WW);

  // Double-buffered zero-padded row buffers: [buf][img][PADK + col]
  __shared__ float sh[2][2][WW + 2 * PADK];
  if (c < PADK) {
#pragma unroll
    for (int bi = 0; bi < 2; ++bi)
#pragma unroll
      for (int im = 0; im < 2; ++im) {
        sh[bi][im][c] = 0.f;
        sh[bi][im][WW + PADK + c] = 0.f;
      }
  }

  // Vertical shift-rings for the 5 horizontal conv terms.
  float r1[KS], r2[KS], r11[KS], r22[KS], r12[KS];
  float local = 0.f;

  for (int i = 0; i < TH + 2 * PADK; ++i) {
    const int rr = r0 - PADK + i;
    float a = 0.f, bb = 0.f;
    if (rr >= 0 && rr < HH) {
      a  = p1[(size_t)rr * WW + c];
      bb = p2[(size_t)rr * WW + c];
    }
    const int buf = i & 1;
    sh[buf][0][PADK + c] = a;
    sh[buf][1][PADK + c] = bb;
    __syncthreads();   // covers pad-init before first read; dbl-buffer => 1 sync/row

    float h1 = 0.f, h2 = 0.f, h11 = 0.f, h22 = 0.f, h12 = 0.f;
#pragma unroll
    for (int k = 0; k < KS; ++k) {
      const float av = sh[buf][0][c + k];
      const float bv = sh[buf][1][c + k];
      const float w  = g[k];
      const float aw = av * w;
      const float bw = bv * w;
      h1  += aw;
      h2  += bw;
      h11 += aw * av;
      h22 += bw * bv;
      h12 += aw * bv;
    }

    // shift ring (static indices after unroll -> pure v_mov, no scratch)
#pragma unroll
    for (int k = 0; k < KS - 1; ++k) {
      r1[k]  = r1[k + 1];  r2[k]  = r2[k + 1];  r11[k] = r11[k + 1];
      r22[k] = r22[k + 1]; r12[k] = r12[k + 1];
    }
    r1[KS - 1] = h1;  r2[KS - 1] = h2;  r11[KS - 1] = h11;
    r22[KS - 1] = h22; r12[KS - 1] = h12;

    if (i >= 2 * PADK) {
      float mu1 = 0.f, mu2 = 0.f, m11 = 0.f, m22 = 0.f, m12 = 0.f;
#pragma unroll
      for (int k = 0; k < KS; ++k) {
        const float w = g[k];
        mu1 += w * r1[k];
        mu2 += w * r2[k];
        m11 += w * r11[k];
        m22 += w * r22[k];
        m12 += w * r12[k];
      }
      const float mu1s = mu1 * mu1;
      const float mu2s = mu2 * mu2;
      const float mu12 = mu1 * mu2;
      const float s11 = m11 - mu1s;
      const float s22 = m22 - mu2s;
      const float s12 = m12 - mu12;
      const float C1 = 1e-4f, C2 = 9e-4f;
      const float num = (2.f * mu12 + C1) * (2.f * s12 + C2);
      const float den = (mu1s + mu2s + C1) * (s11 + s22 + C2);
      local += num / den;
    }
  }

  // Block reduction: wave64 shuffle -> LDS -> one double atomic per block.
#pragma unroll
  for (int off = 32; off > 0; off >>= 1) local += __shfl_down(local, off, 64);

  __shared__ float wsum[WW / 64];
  const int wave = threadIdx.x >> 6;
  const int lane = threadIdx.x & 63;
  if (lane == 0) wsum[wave] = local;
  __syncthreads();
  if (threadIdx.x == 0) {
    float s = 0.f;
#pragma unroll
    for (int w = 0; w < WW / 64; ++w) s += wsum[w];
    atomicAdd(accum, (double)s);
  }
}

__global__ void ssim_final_kernel(const double* __restrict__ accum,
                                  float* __restrict__ out) {
  out[0] = 1.0f - (float)(accum[0] / NPIX);
}

extern "C" void kernel_launch(void* const* d_in, const int* in_sizes, int n_in,
                              void* d_out, int out_size, void* d_ws, size_t ws_size,
                              hipStream_t stream) {
  const float* img1 = (const float*)d_in[0];
  const float* img2 = (const float*)d_in[1];
  double* accum = (double*)d_ws;
  hipMemsetAsync(accum, 0, sizeof(double), stream);

  dim3 grid(HH / TH, BATCH);
  ssim_main_kernel<<<grid, WW, 0, stream>>>(img1, img2, accum);
  ssim_final_kernel<<<1, 1, 0, stream>>>(accum, (float*)d_out);
}

// Round 2
// 191.702 us; speedup vs baseline: 1.3156x; 1.3156x over previous
//
#include <hip/hip_runtime.h>

#define BATCH 64
#define HH 512
#define WW 512
#define TH 32          // output rows per block strip
#define KS 11
#define PADK 5
#define NPIX (64.0 * 512.0 * 512.0)
#define LROW (WW + 2 * PADK)   // 522 float2 slots per row buffer

// One block: 512 threads = one full image row; strip of TH=32 output rows.
// Separable 11x11 Gaussian conv of {a, b, a^2, b^2, ab}:
//   - rows staged as packed float2{a,b} into double-buffered LDS (ds_read_b64)
//   - horizontal 11-tap conv in registers
//   - vertical 11-tap via register ring with STATIC rotation (11-phase unroll)
// then pointwise SSIM, block reduce, one atomicAdd(double) per block.
__global__ void __launch_bounds__(WW) ssim_main_kernel(
    const float* __restrict__ img1, const float* __restrict__ img2,
    double* __restrict__ accum) {
  // Gaussian(sigma=1.5, K=11) weights, normalized; precomputed in fp64.
  // (rel err vs numpy fp64 < 1e-6; threshold is 2e-2 -> irrelevant)
  constexpr float G[KS] = {
      0.00102838f, 0.00759884f, 0.03600087f, 0.10936069f, 0.21300553f,
      0.26601172f, 0.21300553f, 0.10936069f, 0.03600087f, 0.00759884f,
      0.00102838f};

  const int c  = threadIdx.x;            // column 0..511
  const int r0 = blockIdx.x * TH;        // first output row of strip
  const int b  = blockIdx.y;             // batch index

  const float* __restrict__ p1 = img1 + (size_t)b * (HH * WW);
  const float* __restrict__ p2 = img2 + (size_t)b * (HH * WW);

  // Double-buffered zero-padded packed row buffers.
  __shared__ float2 sh[2][LROW];
  if (c < PADK) {
#pragma unroll
    for (int bi = 0; bi < 2; ++bi) {
      sh[bi][c] = make_float2(0.f, 0.f);
      sh[bi][WW + PADK + c] = make_float2(0.f, 0.f);
    }
  }

  // Vertical ring: slot s holds horizontal-conv results of row with i%11==s.
  float r1[KS], r2[KS], r11[KS], r22[KS], r12[KS];
#pragma unroll
  for (int k = 0; k < KS; ++k) { r1[k]=0.f; r2[k]=0.f; r11[k]=0.f; r22[k]=0.f; r12[k]=0.f; }

  float local = 0.f;

  // Prefetch row r0-5 (rr < HH always; only low guard needed).
  float pa = 0.f, pb = 0.f;
  {
    const int rr = r0 - PADK;
    if (rr >= 0) {
      const int off = rr * WW + c;
      pa = p1[off];
      pb = p2[off];
    }
  }

  for (int ii = 0; ii < 4; ++ii) {
#pragma unroll
    for (int p = 0; p < KS; ++p) {
      const int i = ii * KS + p;          // 0..43 ; i % 11 == p (static)
      const int buf = i & 1;

      // Stage current row; prefetch next (one iteration of latency hiding).
      const float ca = pa, cb = pb;
      {
        const int rn = r0 - PADK + i + 1;
        pa = 0.f; pb = 0.f;
        if (rn >= 0 && rn < HH) {         // wave-uniform branch
          const int off = rn * WW + c;
          pa = p1[off];
          pb = p2[off];
        }
      }

      sh[buf][PADK + c] = make_float2(ca, cb);
      __syncthreads();  // dbuf => single barrier/iter is safe (see analysis)

      // Horizontal 11-tap conv of the 5 signals.
      float h1 = 0.f, h2 = 0.f, h11 = 0.f, h22 = 0.f, h12 = 0.f;
#pragma unroll
      for (int k = 0; k < KS; ++k) {
        const float2 v = sh[buf][c + k];
        const float w  = G[k];
        const float aw = v.x * w;
        const float bw = v.y * w;
        h1  += aw;
        h2  += bw;
        h11 = fmaf(aw, v.x, h11);
        h22 = fmaf(bw, v.y, h22);
        h12 = fmaf(aw, v.y, h12);
      }

      // Static ring write (slot p) — no shifting.
      r1[p] = h1; r2[p] = h2; r11[p] = h11; r22[p] = h22; r12[p] = h12;

      if (i >= 2 * PADK && i < TH + 2 * PADK) {   // wave-uniform
        // Vertical 11-tap: row (i-10+t) lives in slot (p+1+t)%11, weight G[t].
        float mu1 = 0.f, mu2 = 0.f, m11 = 0.f, m22 = 0.f, m12 = 0.f;
#pragma unroll
        for (int t = 0; t < KS; ++t) {
          const int s = (p + 1 + t) % KS;  // static after unroll
          const float w = G[t];
          mu1 = fmaf(w, r1[s], mu1);
          mu2 = fmaf(w, r2[s], mu2);
          m11 = fmaf(w, r11[s], m11);
          m22 = fmaf(w, r22[s], m22);
          m12 = fmaf(w, r12[s], m12);
        }
        const float mu1s = mu1 * mu1;
        const float mu2s = mu2 * mu2;
        const float mu12 = mu1 * mu2;
        const float s11 = m11 - mu1s;
        const float s22 = m22 - mu2s;
        const float s12 = m12 - mu12;
        const float C1 = 1e-4f, C2 = 9e-4f;
        const float num = fmaf(2.f, mu12, C1) * fmaf(2.f, s12, C2);
        const float den = (mu1s + mu2s + C1) * (s11 + s22 + C2);
        local = fmaf(num, __builtin_amdgcn_rcpf(den), local);
      }
    }
  }

  // Block reduction: wave64 shuffle -> LDS -> one double atomic per block.
#pragma unroll
  for (int off = 32; off > 0; off >>= 1) local += __shfl_down(local, off, 64);

  __shared__ float wsum[WW / 64];
  const int wave = threadIdx.x >> 6;
  const int lane = threadIdx.x & 63;
  if (lane == 0) wsum[wave] = local;
  __syncthreads();
  if (threadIdx.x == 0) {
    float s = 0.f;
#pragma unroll
    for (int w = 0; w < WW / 64; ++w) s += wsum[w];
    atomicAdd(accum, (double)s);
  }
}

__global__ void ssim_final_kernel(const double* __restrict__ accum,
                                  float* __restrict__ out) {
  out[0] = 1.0f - (float)(accum[0] / NPIX);
}

extern "C" void kernel_launch(void* const* d_in, const int* in_sizes, int n_in,
                              void* d_out, int out_size, void* d_ws, size_t ws_size,
                              hipStream_t stream) {
  const float* img1 = (const float*)d_in[0];
  const float* img2 = (const float*)d_in[1];
  double* accum = (double*)d_ws;
  hipMemsetAsync(accum, 0, sizeof(double), stream);

  dim3 grid(HH / TH, BATCH);
  ssim_main_kernel<<<grid, WW, 0, stream>>>(img1, img2, accum);
  ssim_final_kernel<<<1, 1, 0, stream>>>(accum, (float*)d_out);
}

// Round 3
// 184.316 us; speedup vs baseline: 1.3683x; 1.0401x over previous
//
#include <hip/hip_runtime.h>

#define BATCH 64
#define HH 512
#define WW 512
#define TH 32          // output rows per block strip
#define KS 11
#define PADK 5
#define RCH 4          // rows staged per barrier (chunk)
#define NCH 11         // chunks per strip: 44 input rows = TH + 2*PADK + 2 (tail guarded)
#define NPIX (64.0 * 512.0 * 512.0)
#define LROW (WW + 2 * PADK)   // 522 float4 slots per row

// One block: 512 threads = one image row; strip of TH=32 output rows.
// Key reformulation: SSIM uses only mu1, mu2, E[a^2+b^2], E[ab] -> stage
// float4{a, b, a^2+b^2, ab} per pixel; both separable conv passes are
// 4 fma/tap. Rows staged in 4-row double-buffered chunks (1 barrier per
// chunk, global prefetch a full chunk ahead). Vertical 11-tap via register
// ring with static slots (full 44-iter unroll, 4 and 11 coprime -> i%11
// resolves statically).
__global__ void __launch_bounds__(WW, 4) ssim_main_kernel(
    const float* __restrict__ img1, const float* __restrict__ img2,
    double* __restrict__ accum) {
  // Gaussian(sigma=1.5, K=11), normalized (fp64-precomputed).
  constexpr float G[KS] = {
      0.00102838f, 0.00759884f, 0.03600087f, 0.10936069f, 0.21300553f,
      0.26601172f, 0.21300553f, 0.10936069f, 0.03600087f, 0.00759884f,
      0.00102838f};

  const int c  = threadIdx.x;            // column 0..511
  const int r0 = blockIdx.x * TH;        // first output row of strip
  const int b  = blockIdx.y;             // batch index

  const float* __restrict__ p1 = img1 + (size_t)b * (HH * WW);
  const float* __restrict__ p2 = img2 + (size_t)b * (HH * WW);

  // Double-buffered 4-row staged chunks, zero-padded horizontally.
  __shared__ float4 s4[2][RCH][LROW];
  if (c < PADK) {
#pragma unroll
    for (int bi = 0; bi < 2; ++bi)
#pragma unroll
      for (int r = 0; r < RCH; ++r) {
        s4[bi][r][c]             = make_float4(0.f, 0.f, 0.f, 0.f);
        s4[bi][r][WW + PADK + c] = make_float4(0.f, 0.f, 0.f, 0.f);
      }
  }

  // Vertical ring: slot (i % 11) holds h-conv of input row i. 4 signals.
  float rA[KS], rB[KS], rQ[KS], rP[KS];
  float local = 0.f;

  // Prefetch chunk 0 (input rows i = 0..3, image rows r0-5 .. r0-2).
  float pa[RCH], pb[RCH];
#pragma unroll
  for (int r = 0; r < RCH; ++r) {
    const int rr = r0 - PADK + r;
    pa[r] = 0.f; pb[r] = 0.f;
    if (rr >= 0 && rr < HH) {
      const int off = rr * WW + c;
      pa[r] = p1[off];
      pb[r] = p2[off];
    }
  }

#pragma unroll
  for (int ii = 0; ii < NCH; ++ii) {
    const int buf = ii & 1;

    // Stage chunk ii from prefetch regs: {a, b, a^2+b^2, ab}.
#pragma unroll
    for (int r = 0; r < RCH; ++r) {
      const float a = pa[r], bb = pb[r];
      s4[buf][r][PADK + c] = make_float4(a, bb, fmaf(a, a, bb * bb), a * bb);
    }
    __syncthreads();   // one barrier per chunk (dbuf: next write hits other buf)

    // Prefetch chunk ii+1 (a full chunk of compute ahead of its use).
    if (ii + 1 < NCH) {
#pragma unroll
      for (int r = 0; r < RCH; ++r) {
        const int rr = r0 - PADK + (ii + 1) * RCH + r;
        pa[r] = 0.f; pb[r] = 0.f;
        if (rr >= 0 && rr < HH) {
          const int off = rr * WW + c;
          pa[r] = p1[off];
          pb[r] = p2[off];
        }
      }
    }

    // Compute the 4 rows of chunk ii.
#pragma unroll
    for (int p = 0; p < RCH; ++p) {
      const int i = ii * RCH + p;        // static after full unroll

      // Horizontal 11-tap conv of the 4 signals: 1 b128 + 4 fma per tap.
      float h1 = 0.f, h2 = 0.f, hq = 0.f, hp = 0.f;
#pragma unroll
      for (int k = 0; k < KS; ++k) {
        const float4 v = s4[buf][p][c + k];
        const float w  = G[k];
        h1 = fmaf(w, v.x, h1);
        h2 = fmaf(w, v.y, h2);
        hq = fmaf(w, v.z, hq);
        hp = fmaf(w, v.w, hp);
      }

      rA[i % KS] = h1; rB[i % KS] = h2; rQ[i % KS] = hq; rP[i % KS] = hp;

      if (i >= 2 * PADK && i < TH + 2 * PADK) {   // static guard
        // Vertical 11-tap: row (i-10+t) is in slot (i+1+t)%11.
        float mu1 = 0.f, mu2 = 0.f, mq = 0.f, mp = 0.f;
#pragma unroll
        for (int t = 0; t < KS; ++t) {
          const int s = (i + 1 + t) % KS;  // static
          const float w = G[t];
          mu1 = fmaf(w, rA[s], mu1);
          mu2 = fmaf(w, rB[s], mu2);
          mq  = fmaf(w, rQ[s], mq);
          mp  = fmaf(w, rP[s], mp);
        }
        const float mu1s = mu1 * mu1;
        const float mu2s = mu2 * mu2;
        const float mu12 = mu1 * mu2;
        const float s12 = mp - mu12;            // sigma12
        const float sqq = mq - mu1s - mu2s;     // sigma1^2 + sigma2^2
        const float C1 = 1e-4f, C2 = 9e-4f;
        const float num = fmaf(2.f, mu12, C1) * fmaf(2.f, s12, C2);
        const float den = (mu1s + mu2s + C1) * (sqq + C2);
        local = fmaf(num, __builtin_amdgcn_rcpf(den), local);
      }
    }
  }

  // Block reduction: wave64 shuffle -> LDS -> one double atomic per block.
#pragma unroll
  for (int off = 32; off > 0; off >>= 1) local += __shfl_down(local, off, 64);

  __shared__ float wsum[WW / 64];
  const int wave = threadIdx.x >> 6;
  const int lane = threadIdx.x & 63;
  if (lane == 0) wsum[wave] = local;
  __syncthreads();
  if (threadIdx.x == 0) {
    float s = 0.f;
#pragma unroll
    for (int w = 0; w < WW / 64; ++w) s += wsum[w];
    atomicAdd(accum, (double)s);
  }
}

__global__ void ssim_final_kernel(const double* __restrict__ accum,
                                  float* __restrict__ out) {
  out[0] = 1.0f - (float)(accum[0] / NPIX);
}

extern "C" void kernel_launch(void* const* d_in, const int* in_sizes, int n_in,
                              void* d_out, int out_size, void* d_ws, size_t ws_size,
                              hipStream_t stream) {
  const float* img1 = (const float*)d_in[0];
  const float* img2 = (const float*)d_in[1];
  double* accum = (double*)d_ws;
  hipMemsetAsync(accum, 0, sizeof(double), stream);

  dim3 grid(HH / TH, BATCH);
  ssim_main_kernel<<<grid, WW, 0, stream>>>(img1, img2, accum);
  ssim_final_kernel<<<1, 1, 0, stream>>>(accum, (float*)d_out);
}